// Round 17
// baseline (405.919 us; speedup 1.0000x reference)
//
#include <hip/hip_runtime.h>
#include <math.h>

#define B_   4
#define T_   1024
#define MAXH 2048
#define NKV  8

typedef unsigned int uint;
typedef unsigned short ushort;
typedef __attribute__((ext_vector_type(8))) short bf16x8;
typedef __attribute__((ext_vector_type(4))) float f32x4;

__device__ __forceinline__ ushort f2bf(float f) {
    uint u = __float_as_uint(f);
    u += 0x7fffu + ((u >> 16) & 1u);   // RNE
    return (ushort)(u >> 16);
}

__device__ __forceinline__ uint cvtpk_bf16(float lo, float hi) {
    uint r;
    asm("v_cvt_pk_bf16_f32 %0, %1, %2" : "=v"(r) : "v"(lo), "v"(hi));
    return r;
}

// ---------------- Q/K mix body (verified) ----------------
template<int H1>
__device__ __forceinline__ void mixqk_body(
    int bt, const float* __restrict__ src, ushort* __restrict__ dst0,
    ushort* __restrict__ dst1, const float* __restrict__ wts, float* L)
{
    const int t = bt & (T_ - 1), b = bt >> 10;
    const float* row = src + (size_t)bt * MAXH;
    const int tid = threadIdx.x;
#pragma unroll
    for (int i = 0; i < 2; i++) {
        int idx = tid + i * 256;
        *(float4*)&L[idx * 4] = *(const float4*)&row[idx * 4];
    }
    __syncthreads();
    const float w0s = wts[0], w0b = wts[1], w1s = wts[2], w1b = wts[3];
    const float tf = (float)t;
    constexpr float LG = 13.287712379549449f;   // log2(10000)

#pragma unroll
    for (int i = 0; i < 4; i++) {
        int p = tid + i * 256;
        int hh = p >> 7, jh = p & 127;
        float ab = tf * exp2f((float)jh * (-2.f * LG / 256.f));
        float sb = __sinf(ab), cb = __cosf(ab);
        float x0 = L[hh * 256 + jh], x1 = L[hh * 256 + jh + 128];
        float v0 = w0b * (x0 * cb - x1 * sb);
        float v1 = w0b * (x1 * cb + x0 * sb);
        float as = tf * exp2f((float)(jh & 63) * (-2.f * LG / 128.f));
        float ss = __sinf(as), cs = __cosf(as);
        float y  = L[hh * 128 + jh];
        float yr = (jh < 64) ? -L[hh * 128 + jh + 64] : L[hh * 128 + jh - 64];
        v0 += w0s * (y * cs + yr * ss);
        ushort* d0 = dst0 + (((size_t)b * 8 + hh) * T_ + t) * 256;
        d0[jh] = f2bf(v0); d0[jh + 128] = f2bf(v1);
    }
#pragma unroll
    for (int i = 0; i < H1 / 4; i++) {
        int p = tid + i * 256;
        int h = p >> 6, jh = p & 63;
        float ab = tf * exp2f((float)jh * (-2.f * LG / 128.f));
        float sb = __sinf(ab), cb = __cosf(ab);
        float x0 = L[h * 128 + jh], x1 = L[h * 128 + jh + 64];
        float v0 = w1b * (x0 * cb - x1 * sb);
        float v1 = w1b * (x1 * cb + x0 * sb);
        float as = tf * exp2f((float)(jh & 31) * (-2.f * LG / 64.f));
        float ss = __sinf(as), cs = __cosf(as);
        float y  = L[h * 64 + jh];
        float yr = (jh < 32) ? -L[h * 64 + jh + 32] : L[h * 64 + jh - 32];
        v0 += w1s * (y * cs + yr * ss);
        ushort* d1 = dst1 + (((size_t)b * H1 + h) * T_ + t) * 128;
        d1[jh] = f2bf(v0); d1[jh + 64] = f2bf(v1);
    }
}

// ---------------- V mix transposed body (verified) ----------------
template<int DMAX>
__device__ __forceinline__ void mixv_body(
    int bid, const float* __restrict__ src, ushort* __restrict__ dst,
    const float* __restrict__ wts, int wsi, int wbi, ushort* tile /* [32][33] */)
{
    constexpr int DS = DMAX / 2;
    constexpr int DDN = DMAX / 32;
    int dd = bid % DDN;  bid /= DDN;
    int tt = bid & 31;   int bk = bid >> 5;
    int b = bk >> 3, kh = bk & 7;
    int tid = threadIdx.x;
    float wb = wts[wbi], wsm = wts[wsi];

    int jloc = tid & 31;
    int j = dd * 32 + jloc;
#pragma unroll
    for (int p = 0; p < 4; p++) {
        int tl = (tid >> 5) + p * 8;
        const float* row = src + ((size_t)b * T_ + tt * 32 + tl) * MAXH;
        float v = wb * row[kh * DMAX + j];
        if (j < DS) v += wsm * row[kh * DS + j];
        tile[tl * 33 + jloc] = f2bf(v);
    }
    __syncthreads();
    int tl = tid & 31;
#pragma unroll
    for (int p = 0; p < 4; p++) {
        int jl = (tid >> 5) + p * 8;
        dst[((size_t)bk * DMAX + dd * 32 + jl) * T_ + tt * 32 + tl] = tile[tl * 33 + jl];
    }
}

// ---------------- single prep dispatch: all mixes ----------------
__global__ __launch_bounds__(256) void mix_all(
    const float* __restrict__ q_m, const float* __restrict__ k_m, const float* __restrict__ v_m,
    const float* __restrict__ wts,
    ushort* qmix0, ushort* kmix0, ushort* vt0,
    ushort* qmix1, ushort* kmix1, ushort* vt1)
{
    __shared__ float L[2048];
    const int bid = blockIdx.x;
    if (bid < 4096) {
        mixqk_body<16>(bid, q_m, qmix0, qmix1, wts, L);
    } else if (bid < 8192) {
        mixqk_body<8>(bid - 4096, k_m, kmix0, kmix1, wts, L);
    } else if (bid < 16384) {
        mixv_body<256>(bid - 8192, v_m, vt0, wts, 0, 1, (ushort*)L);
    } else {
        mixv_body<128>(bid - 16384, v_m, vt1, wts, 2, 3, (ushort*)L);
    }
}

// ---------------- attention instance(s) for one 32-key tile (round-16, verified) ----------------
// Swapped QK^T (S^T = mfma(K,Q)) + fixed-reference softmax + in-register P->A-frag
// lane exchange + all-ones-B row-sum MFMA. NQ heads share K/V fragment reads.
template<int NC, int NSUB, int RS, int NQ>
__device__ __forceinline__ void attn_inst(
    const bf16x8* qf, f32x4* acc, f32x4* accl,
    const ushort* lds, int ksbase, int vtbase,
    float scale2, int qw, int kt32, int qtr, int l16)
{
    const bool full = (kt32 + 31) <= qw;
    f32x4 s0[NQ], s1[NQ];
#pragma unroll
    for (int qi = 0; qi < NQ; qi++) { s0[qi] = (f32x4){0.f,0.f,0.f,0.f}; s1[qi] = (f32x4){0.f,0.f,0.f,0.f}; }

    __builtin_amdgcn_s_setprio(1);
#pragma unroll
    for (int c = 0; c < NC; c++) {
        int ch = ((c * 4 + qtr) ^ (l16 & 7)) * 8;
        bf16x8 k0 = *(const bf16x8*)&lds[ksbase + l16 * RS + ch];
        bf16x8 k1 = *(const bf16x8*)&lds[ksbase + (16 + l16) * RS + ch];
#pragma unroll
        for (int qi = 0; qi < NQ; qi++) {
            s0[qi] = __builtin_amdgcn_mfma_f32_16x16x32_bf16(k0, qf[qi * NC + c], s0[qi], 0, 0, 0);
            s1[qi] = __builtin_amdgcn_mfma_f32_16x16x32_bf16(k1, qf[qi * NC + c], s1[qi], 0, 0, 0);
        }
    }
    __builtin_amdgcn_s_setprio(0);

    bf16x8 pa[NQ];
    const bool lohalf = (qtr < 2);
    const bool evengrp = !(qtr & 1);
#pragma unroll
    for (int qi = 0; qi < NQ; qi++) {
        float p0[4], p1[4];
#pragma unroll
        for (int rr = 0; rr < 4; rr++) {
            p0[rr] = exp2f(s0[qi][rr] * scale2);
            p1[rr] = exp2f(s1[qi][rr] * scale2);
            if (!full) {
                int qq = qw + l16;
                if (kt32 + qtr * 4 + rr > qq)      p0[rr] = 0.f;
                if (kt32 + 16 + qtr * 4 + rr > qq) p1[rr] = 0.f;
            }
        }
        uint u0 = cvtpk_bf16(p0[0], p0[1]);
        uint u1 = cvtpk_bf16(p0[2], p0[3]);
        uint u2 = cvtpk_bf16(p1[0], p1[1]);
        uint u3 = cvtpk_bf16(p1[2], p1[3]);
        uint su0 = __shfl_xor(u0, 32), su1 = __shfl_xor(u1, 32);
        uint su2 = __shfl_xor(u2, 32), su3 = __shfl_xor(u3, 32);
        uint X1 = lohalf ? u0 : su2;
        uint Y1 = lohalf ? u1 : su3;
        uint X2 = lohalf ? su0 : u2;
        uint Y2 = lohalf ? su1 : u3;
        uint sX1 = __shfl_xor(X1, 16), sY1 = __shfl_xor(Y1, 16);
        uint sX2 = __shfl_xor(X2, 16), sY2 = __shfl_xor(Y2, 16);
        union { uint4 w; bf16x8 v; } cvt;
        cvt.w.x = evengrp ? X1  : sX2;
        cvt.w.y = evengrp ? Y1  : sY2;
        cvt.w.z = evengrp ? sX1 : X2;
        cvt.w.w = evengrp ? sY1 : Y2;
        pa[qi] = cvt.v;
    }

    bf16x8 ones;
#pragma unroll
    for (int j = 0; j < 8; j++) ones[j] = (short)0x3f80;   // bf16 1.0
    __builtin_amdgcn_s_setprio(1);
#pragma unroll
    for (int s = 0; s < NSUB; s++) {
        bf16x8 vb = *(const bf16x8*)&lds[vtbase + (s * 16 + l16) * 32 + ((qtr ^ (l16 & 3)) * 8)];
#pragma unroll
        for (int qi = 0; qi < NQ; qi++)
            acc[qi * NSUB + s] = __builtin_amdgcn_mfma_f32_16x16x32_bf16(pa[qi], vb, acc[qi * NSUB + s], 0, 0, 0);
    }
#pragma unroll
    for (int qi = 0; qi < NQ; qi++)
        accl[qi] = __builtin_amdgcn_mfma_f32_16x16x32_bf16(pa[qi], ones, accl[qi], 0, 0, 0);
    __builtin_amdgcn_s_setprio(0);
}

// ---------------- split-k fused attention: block = (b, kh, qt); 16 waves (1024 thr) ----------------
// Two 8-wave groups: group g processes k-tiles {g, g+2, ...} (nkt even -> exact split,
// niter = qt+1 each) in its private 48KB LDS half. Fixed-ref softmax partials are
// ADDITIVE across key ranges -> in-LDS pairwise combine (wave w <-> w-8) at the end,
// then store/sync/add epilogue by group 0. Critical path halves vs 8-wave blocks.
__global__ __launch_bounds__(1024) void attn_fused(
    const ushort* __restrict__ qmix0, const ushort* __restrict__ kmix0, const ushort* __restrict__ vt0,
    const ushort* __restrict__ qmix1, const ushort* __restrict__ kmix1, const ushort* __restrict__ vt1,
    float* __restrict__ out)
{
    __shared__ alignas(16) ushort lds[49152];   // 96KB: 2 groups x 24576 ushorts
    constexpr int GSZ = 24576;
    constexpr int KS0 = 0, KS1 = 8192, VT0 = 12288, VT1 = 20480;

    const int bid = blockIdx.x;
    const int half = bid >> 8;
    const int ipair = (bid >> 5) & 7;
    const int idx = bid & 31;
    const int b = idx >> 3, kh = idx & 7;
    const int qt = half ? ipair : 15 - ipair;

    const int tid = threadIdx.x;
    const int wid = tid >> 6;
    const int grp = wid >> 3;          // k-split group
    const int wl  = wid & 7;           // wave-in-group
    const int gtid = tid & 511;        // thread-in-group
    const int lane = tid & 63;
    const int qtr = lane >> 4, l16 = lane & 15;
    const int cfg = wl >> 2;
    const int w4 = wl & 3;
    const int lbase = grp * GSZ;

    const ushort* kg0 = kmix0 + ((size_t)b * NKV + kh) * T_ * 256;
    const ushort* vg0 = vt0   + ((size_t)b * NKV + kh) * 256 * T_;
    const ushort* kg1 = kmix1 + ((size_t)b * NKV + kh) * T_ * 128;
    const ushort* vg1 = vt1   + ((size_t)b * NKV + kh) * 128 * T_;

    // staging assignments (512 threads per group)
    const int k0r0 = gtid >> 5,         k0c0 = gtid & 31;
    const int k0r1 = (gtid + 512) >> 5, k0c1 = (gtid + 512) & 31;
    const int v0d0 = gtid >> 2,         v0c0 = gtid & 3;
    const int v0d1 = (gtid + 512) >> 2, v0c1 = (gtid + 512) & 3;
    const int k1r = gtid >> 4, k1c = gtid & 15;
    const int v1d = gtid >> 2, v1c = gtid & 3;

    const int nkt = 2 * qt + 2;
    const int niter = qt + 1;          // tiles per group
    const int qw = qt * 64 + w4 * 16;

    bf16x8 qf[8];
    if (cfg == 0) {
        const ushort* qb = qmix0 + (((size_t)b * 8 + kh) * T_ + qw + l16) * 256 + qtr * 8;
#pragma unroll
        for (int c = 0; c < 8; c++) qf[c] = *(const bf16x8*)(qb + c * 32);
    } else {
#pragma unroll
        for (int hI = 0; hI < 2; hI++) {
            const ushort* qb = qmix1 + (((size_t)b * 16 + 2 * kh + hI) * T_ + qw + l16) * 128 + qtr * 8;
#pragma unroll
            for (int c = 0; c < 4; c++) qf[hI * 4 + c] = *(const bf16x8*)(qb + c * 32);
        }
    }

    f32x4 acc[16];
    f32x4 accl[2] = {{0.f,0.f,0.f,0.f},{0.f,0.f,0.f,0.f}};
#pragma unroll
    for (int s = 0; s < 16; s++) acc[s] = (f32x4){0.f,0.f,0.f,0.f};

    const float scale2_0 = 0.0625f * 1.4426950408889634f;
    const float scale2_1 = 0.08838834764831845f * 1.4426950408889634f;

    uint4 k0a, k0b, v0a, v0b, k1a, v1a;
#define ISSUE(kt_) do {                                                              \
        k0a = *(const uint4*)(kg0 + (size_t)((kt_) * 32 + k0r0) * 256 + k0c0 * 8);   \
        k0b = *(const uint4*)(kg0 + (size_t)((kt_) * 32 + k0r1) * 256 + k0c1 * 8);   \
        v0a = *(const uint4*)(vg0 + (size_t)v0d0 * T_ + (kt_) * 32 + v0c0 * 8);      \
        v0b = *(const uint4*)(vg0 + (size_t)v0d1 * T_ + (kt_) * 32 + v0c1 * 8);      \
        k1a = *(const uint4*)(kg1 + (size_t)((kt_) * 32 + k1r) * 128 + k1c * 8);     \
        v1a = *(const uint4*)(vg1 + (size_t)v1d * T_ + (kt_) * 32 + v1c * 8);        \
    } while (0)

    ISSUE(grp);
    for (int j = 0; j < niter; j++) {
        const int kt = 2 * j + grp;
        // barrier A: all 16 waves done reading LDS from previous iteration (no vmcnt drain).
        asm volatile("s_barrier" ::: "memory");
        *(uint4*)&lds[lbase + KS0 + k0r0 * 256 + ((k0c0 ^ (k0r0 & 7)) * 8)] = k0a;
        *(uint4*)&lds[lbase + KS0 + k0r1 * 256 + ((k0c1 ^ (k0r1 & 7)) * 8)] = k0b;
        *(uint4*)&lds[lbase + VT0 + v0d0 * 32 + ((v0c0 ^ (v0d0 & 3)) * 8)] = v0a;
        *(uint4*)&lds[lbase + VT0 + v0d1 * 32 + ((v0c1 ^ (v0d1 & 3)) * 8)] = v0b;
        *(uint4*)&lds[lbase + KS1 + k1r * 128 + ((k1c ^ (k1r & 7)) * 8)] = k1a;
        *(uint4*)&lds[lbase + VT1 + v1d * 32 + ((v1c ^ (v1d & 3)) * 8)] = v1a;
        if (j + 1 < niter) ISSUE(kt + 2);   // stays in flight across barrier B
        // barrier B: my ds_writes complete (lgkmcnt only), then all waves sync.
        asm volatile("s_waitcnt lgkmcnt(0)" ::: "memory");
        asm volatile("s_barrier" ::: "memory");

        const int kt32 = kt * 32;
        if (kt32 <= qw + 15) {
            if (cfg == 0) {
                attn_inst<8, 16, 256, 1>(qf, acc, accl, lds, lbase + KS0, lbase + VT0,
                                         scale2_0, qw, kt32, qtr, l16);
            } else {
                attn_inst<4, 8, 128, 2>(qf, acc, accl, lds, lbase + KS1, lbase + VT1,
                                        scale2_1, qw, kt32, qtr, l16);
            }
        }
    }
#undef ISSUE

    // ---- cross-group partial combine (fixed-ref softmax partials are additive) ----
    // chunk r: group-1 waves wl in [4r,4r+4) dump acc+accl to LDS (72 f32/lane);
    // matching group-0 waves add. 4*4608 f32 = 18KB per chunk (reuses tile LDS).
    float* ldsF = (float*)lds;
#pragma unroll
    for (int r = 0; r < 2; r++) {
        __syncthreads();
        if (grp == 1 && (wl >> 2) == r) {
            float* dst = &ldsF[(wl & 3) * 4608 + lane * 72];
#pragma unroll
            for (int s = 0; s < 16; s++)
#pragma unroll
                for (int rr = 0; rr < 4; rr++) dst[s * 4 + rr] = acc[s][rr];
#pragma unroll
            for (int qi = 0; qi < 2; qi++)
#pragma unroll
                for (int rr = 0; rr < 4; rr++) dst[64 + qi * 4 + rr] = accl[qi][rr];
        }
        __syncthreads();
        if (grp == 0 && (wl >> 2) == r) {
            const float* src = &ldsF[(wl & 3) * 4608 + lane * 72];
#pragma unroll
            for (int s = 0; s < 16; s++)
#pragma unroll
                for (int rr = 0; rr < 4; rr++) acc[s][rr] += src[s * 4 + rr];
#pragma unroll
            for (int qi = 0; qi < 2; qi++)
#pragma unroll
                for (int rr = 0; rr < 4; rr++) accl[qi][rr] += src[64 + qi * 4 + rr];
        }
    }

    // ---- epilogue by group 0 (totals): cfg0 store, sync, cfg1 add ----
    if (grp == 0 && cfg == 0) {
        float linv[4];
#pragma unroll
        for (int rr = 0; rr < 4; rr++) linv[rr] = 1.f / accl[0][rr];
        float* ob = out + ((size_t)b * T_ + qw) * MAXH + kh * 256;
#pragma unroll
        for (int s = 0; s < 16; s++)
#pragma unroll
            for (int rr = 0; rr < 4; rr++)
                ob[(size_t)(qtr * 4 + rr) * MAXH + s * 16 + l16] = acc[s][rr] * linv[rr];
    }
    __syncthreads();   // cfg0 stores visible before cfg1 accumulates
    if (grp == 0 && cfg == 1) {
        float linva[4], linvb[4];
#pragma unroll
        for (int rr = 0; rr < 4; rr++) { linva[rr] = 1.f / accl[0][rr]; linvb[rr] = 1.f / accl[1][rr]; }
        float* ob = out + ((size_t)b * T_ + qw) * MAXH + kh * 256;
#pragma unroll
        for (int s = 0; s < 8; s++)
#pragma unroll
            for (int rr = 0; rr < 4; rr++)
                ob[(size_t)(qtr * 4 + rr) * MAXH + s * 16 + l16] += acc[s][rr] * linva[rr];
#pragma unroll
        for (int s = 0; s < 8; s++)
#pragma unroll
            for (int rr = 0; rr < 4; rr++)
                ob[(size_t)(qtr * 4 + rr) * MAXH + 128 + s * 16 + l16] += acc[8 + s][rr] * linvb[rr];
    }
}

extern "C" void kernel_launch(void* const* d_in, const int* in_sizes, int n_in,
                              void* d_out, int out_size, void* d_ws, size_t ws_size,
                              hipStream_t stream) {
    const float* q_m = (const float*)d_in[0];
    const float* k_m = (const float*)d_in[1];
    const float* v_m = (const float*)d_in[2];
    const float* wts = (const float*)d_in[3];
    // d_in[4] attention_mask == causal tril (applied analytically)
    // d_in[5] position_ids == arange(T) (pos == t)
    float* out = (float*)d_out;
    ushort* ws = (ushort*)d_ws;

    ushort* qmix0 = ws;                 // (4,8,1024,256)   8M
    ushort* kmix0 = ws + 8388608u;      // (4,8,1024,256)   8M
    ushort* vt0   = ws + 16777216u;     // (4,8,256,1024)   8M (transposed)
    ushort* qmix1 = ws + 25165824u;     // (4,16,1024,128)  8M
    ushort* kmix1 = ws + 33554432u;     // (4,8,1024,128)   4M
    ushort* vt1   = ws + 37748736u;     // (4,8,128,1024)   4M (transposed)

    // weights l: 0:(h8,e1024) 1:(h8,e2048) 2:(h16,e1024) 3:(h16,e2048)
    mix_all<<<dim3(20480), dim3(256), 0, stream>>>(q_m, k_m, v_m, wts,
                                                   qmix0, kmix0, vt0, qmix1, kmix1, vt1);
    attn_fused<<<dim3(512), dim3(1024), 0, stream>>>(qmix0, kmix0, vt0, qmix1, kmix1, vt1, out);
}

// Round 18
// 133.420 us; speedup vs baseline: 3.0424x; 3.0424x over previous
//
#include <hip/hip_runtime.h>
#include <math.h>

#define B_   4
#define T_   1024
#define MAXH 2048
#define NKV  8

typedef unsigned int uint;
typedef unsigned short ushort;
typedef __attribute__((ext_vector_type(8))) short bf16x8;
typedef __attribute__((ext_vector_type(4))) float f32x4;

__device__ __forceinline__ ushort f2bf(float f) {
    uint u = __float_as_uint(f);
    u += 0x7fffu + ((u >> 16) & 1u);   // RNE
    return (ushort)(u >> 16);
}

__device__ __forceinline__ uint cvtpk_bf16(float lo, float hi) {
    uint r;
    asm("v_cvt_pk_bf16_f32 %0, %1, %2" : "=v"(r) : "v"(lo), "v"(hi));
    return r;
}

// ---------------- Q/K mix body (verified) ----------------
template<int H1>
__device__ __forceinline__ void mixqk_body(
    int bt, const float* __restrict__ src, ushort* __restrict__ dst0,
    ushort* __restrict__ dst1, const float* __restrict__ wts, float* L)
{
    const int t = bt & (T_ - 1), b = bt >> 10;
    const float* row = src + (size_t)bt * MAXH;
    const int tid = threadIdx.x;
#pragma unroll
    for (int i = 0; i < 2; i++) {
        int idx = tid + i * 256;
        *(float4*)&L[idx * 4] = *(const float4*)&row[idx * 4];
    }
    __syncthreads();
    const float w0s = wts[0], w0b = wts[1], w1s = wts[2], w1b = wts[3];
    const float tf = (float)t;
    constexpr float LG = 13.287712379549449f;   // log2(10000)

#pragma unroll
    for (int i = 0; i < 4; i++) {
        int p = tid + i * 256;
        int hh = p >> 7, jh = p & 127;
        float ab = tf * exp2f((float)jh * (-2.f * LG / 256.f));
        float sb = __sinf(ab), cb = __cosf(ab);
        float x0 = L[hh * 256 + jh], x1 = L[hh * 256 + jh + 128];
        float v0 = w0b * (x0 * cb - x1 * sb);
        float v1 = w0b * (x1 * cb + x0 * sb);
        float as = tf * exp2f((float)(jh & 63) * (-2.f * LG / 128.f));
        float ss = __sinf(as), cs = __cosf(as);
        float y  = L[hh * 128 + jh];
        float yr = (jh < 64) ? -L[hh * 128 + jh + 64] : L[hh * 128 + jh - 64];
        v0 += w0s * (y * cs + yr * ss);
        ushort* d0 = dst0 + (((size_t)b * 8 + hh) * T_ + t) * 256;
        d0[jh] = f2bf(v0); d0[jh + 128] = f2bf(v1);
    }
#pragma unroll
    for (int i = 0; i < H1 / 4; i++) {
        int p = tid + i * 256;
        int h = p >> 6, jh = p & 63;
        float ab = tf * exp2f((float)jh * (-2.f * LG / 128.f));
        float sb = __sinf(ab), cb = __cosf(ab);
        float x0 = L[h * 128 + jh], x1 = L[h * 128 + jh + 64];
        float v0 = w1b * (x0 * cb - x1 * sb);
        float v1 = w1b * (x1 * cb + x0 * sb);
        float as = tf * exp2f((float)(jh & 31) * (-2.f * LG / 64.f));
        float ss = __sinf(as), cs = __cosf(as);
        float y  = L[h * 64 + jh];
        float yr = (jh < 32) ? -L[h * 64 + jh + 32] : L[h * 64 + jh - 32];
        v0 += w1s * (y * cs + yr * ss);
        ushort* d1 = dst1 + (((size_t)b * H1 + h) * T_ + t) * 128;
        d1[jh] = f2bf(v0); d1[jh + 64] = f2bf(v1);
    }
}

// ---------------- V mix transposed body (verified) ----------------
template<int DMAX>
__device__ __forceinline__ void mixv_body(
    int bid, const float* __restrict__ src, ushort* __restrict__ dst,
    const float* __restrict__ wts, int wsi, int wbi, ushort* tile /* [32][33] */)
{
    constexpr int DS = DMAX / 2;
    constexpr int DDN = DMAX / 32;
    int dd = bid % DDN;  bid /= DDN;
    int tt = bid & 31;   int bk = bid >> 5;
    int b = bk >> 3, kh = bk & 7;
    int tid = threadIdx.x;
    float wb = wts[wbi], wsm = wts[wsi];

    int jloc = tid & 31;
    int j = dd * 32 + jloc;
#pragma unroll
    for (int p = 0; p < 4; p++) {
        int tl = (tid >> 5) + p * 8;
        const float* row = src + ((size_t)b * T_ + tt * 32 + tl) * MAXH;
        float v = wb * row[kh * DMAX + j];
        if (j < DS) v += wsm * row[kh * DS + j];
        tile[tl * 33 + jloc] = f2bf(v);
    }
    __syncthreads();
    int tl = tid & 31;
#pragma unroll
    for (int p = 0; p < 4; p++) {
        int jl = (tid >> 5) + p * 8;
        dst[((size_t)bk * DMAX + dd * 32 + jl) * T_ + tt * 32 + tl] = tile[tl * 33 + jl];
    }
}

// ---------------- single prep dispatch: all mixes ----------------
__global__ __launch_bounds__(256) void mix_all(
    const float* __restrict__ q_m, const float* __restrict__ k_m, const float* __restrict__ v_m,
    const float* __restrict__ wts,
    ushort* qmix0, ushort* kmix0, ushort* vt0,
    ushort* qmix1, ushort* kmix1, ushort* vt1)
{
    __shared__ float L[2048];
    const int bid = blockIdx.x;
    if (bid < 4096) {
        mixqk_body<16>(bid, q_m, qmix0, qmix1, wts, L);
    } else if (bid < 8192) {
        mixqk_body<8>(bid - 4096, k_m, kmix0, kmix1, wts, L);
    } else if (bid < 16384) {
        mixv_body<256>(bid - 8192, v_m, vt0, wts, 0, 1, (ushort*)L);
    } else {
        mixv_body<128>(bid - 16384, v_m, vt1, wts, 2, 3, (ushort*)L);
    }
}

// ---------------- attention instance(s) for one 32-key tile (round-16, verified) ----------------
// Swapped QK^T (S^T = mfma(K,Q)) + fixed-reference softmax + in-register P->A-frag
// lane exchange + all-ones-B row-sum MFMA. NQ heads share K/V fragment reads.
template<int NC, int NSUB, int RS, int NQ>
__device__ __forceinline__ void attn_inst(
    const bf16x8* qf, f32x4* acc, f32x4* accl,
    const ushort* lds, int ksbase, int vtbase,
    float scale2, int qw, int kt32, int qtr, int l16)
{
    const bool full = (kt32 + 31) <= qw;
    f32x4 s0[NQ], s1[NQ];
#pragma unroll
    for (int qi = 0; qi < NQ; qi++) { s0[qi] = (f32x4){0.f,0.f,0.f,0.f}; s1[qi] = (f32x4){0.f,0.f,0.f,0.f}; }

    __builtin_amdgcn_s_setprio(1);
#pragma unroll
    for (int c = 0; c < NC; c++) {
        int ch = ((c * 4 + qtr) ^ (l16 & 7)) * 8;
        bf16x8 k0 = *(const bf16x8*)&lds[ksbase + l16 * RS + ch];
        bf16x8 k1 = *(const bf16x8*)&lds[ksbase + (16 + l16) * RS + ch];
#pragma unroll
        for (int qi = 0; qi < NQ; qi++) {
            s0[qi] = __builtin_amdgcn_mfma_f32_16x16x32_bf16(k0, qf[qi * NC + c], s0[qi], 0, 0, 0);
            s1[qi] = __builtin_amdgcn_mfma_f32_16x16x32_bf16(k1, qf[qi * NC + c], s1[qi], 0, 0, 0);
        }
    }
    __builtin_amdgcn_s_setprio(0);

    bf16x8 pa[NQ];
    const bool lohalf = (qtr < 2);
    const bool evengrp = !(qtr & 1);
#pragma unroll
    for (int qi = 0; qi < NQ; qi++) {
        float p0[4], p1[4];
#pragma unroll
        for (int rr = 0; rr < 4; rr++) {
            p0[rr] = exp2f(s0[qi][rr] * scale2);
            p1[rr] = exp2f(s1[qi][rr] * scale2);
            if (!full) {
                int qq = qw + l16;
                if (kt32 + qtr * 4 + rr > qq)      p0[rr] = 0.f;
                if (kt32 + 16 + qtr * 4 + rr > qq) p1[rr] = 0.f;
            }
        }
        uint u0 = cvtpk_bf16(p0[0], p0[1]);
        uint u1 = cvtpk_bf16(p0[2], p0[3]);
        uint u2 = cvtpk_bf16(p1[0], p1[1]);
        uint u3 = cvtpk_bf16(p1[2], p1[3]);
        uint su0 = __shfl_xor(u0, 32), su1 = __shfl_xor(u1, 32);
        uint su2 = __shfl_xor(u2, 32), su3 = __shfl_xor(u3, 32);
        uint X1 = lohalf ? u0 : su2;
        uint Y1 = lohalf ? u1 : su3;
        uint X2 = lohalf ? su0 : u2;
        uint Y2 = lohalf ? su1 : u3;
        uint sX1 = __shfl_xor(X1, 16), sY1 = __shfl_xor(Y1, 16);
        uint sX2 = __shfl_xor(X2, 16), sY2 = __shfl_xor(Y2, 16);
        union { uint4 w; bf16x8 v; } cvt;
        cvt.w.x = evengrp ? X1  : sX2;
        cvt.w.y = evengrp ? Y1  : sY2;
        cvt.w.z = evengrp ? sX1 : X2;
        cvt.w.w = evengrp ? sY1 : Y2;
        pa[qi] = cvt.v;
    }

    bf16x8 ones;
#pragma unroll
    for (int j = 0; j < 8; j++) ones[j] = (short)0x3f80;   // bf16 1.0
    __builtin_amdgcn_s_setprio(1);
#pragma unroll
    for (int s = 0; s < NSUB; s++) {
        bf16x8 vb = *(const bf16x8*)&lds[vtbase + (s * 16 + l16) * 32 + ((qtr ^ (l16 & 3)) * 8)];
#pragma unroll
        for (int qi = 0; qi < NQ; qi++)
            acc[qi * NSUB + s] = __builtin_amdgcn_mfma_f32_16x16x32_bf16(pa[qi], vb, acc[qi * NSUB + s], 0, 0, 0);
    }
#pragma unroll
    for (int qi = 0; qi < NQ; qi++)
        accl[qi] = __builtin_amdgcn_mfma_f32_16x16x32_bf16(pa[qi], ones, accl[qi], 0, 0, 0);
    __builtin_amdgcn_s_setprio(0);
}

// ---------------- fused attention: block = (b, kh, qt); 8 waves; DOUBLE-BUFFERED LDS ----------------
// waves 0-3: cfg0 head kh (d=256); waves 4-7: cfg1 heads 2kh,2kh+1 (d=128), shared K/V reads.
// Iteration j: compute tile j from buf[j&1] while writing tile j+1 into buf[(j+1)&1]
// -> ONE barrier per iteration (lgkmcnt-only wait; vm loads stay in flight).
// 96KB LDS -> 1 block/CU, blocks run serially per CU; qt-descending queue = LPT balance.
__global__ __launch_bounds__(512, 1) void attn_fused(
    const ushort* __restrict__ qmix0, const ushort* __restrict__ kmix0, const ushort* __restrict__ vt0,
    const ushort* __restrict__ qmix1, const ushort* __restrict__ kmix1, const ushort* __restrict__ vt1,
    float* __restrict__ out)
{
    __shared__ alignas(16) ushort lds[49152];   // 96KB: 2 buffers x 24576 ushorts
    constexpr int BSZ = 24576;
    constexpr int KS0 = 0, KS1 = 8192, VT0 = 12288, VT1 = 20480;

    const int bid = blockIdx.x;
    const int half = bid >> 8;
    const int ipair = (bid >> 5) & 7;
    const int idx = bid & 31;
    const int b = idx >> 3, kh = idx & 7;
    const int qt = half ? ipair : 15 - ipair;

    const int tid = threadIdx.x;
    const int wid = tid >> 6, lane = tid & 63;
    const int qtr = lane >> 4, l16 = lane & 15;
    const int cfg = wid >> 2;
    const int w4 = wid & 3;

    const ushort* kg0 = kmix0 + ((size_t)b * NKV + kh) * T_ * 256;
    const ushort* vg0 = vt0   + ((size_t)b * NKV + kh) * 256 * T_;
    const ushort* kg1 = kmix1 + ((size_t)b * NKV + kh) * T_ * 128;
    const ushort* vg1 = vt1   + ((size_t)b * NKV + kh) * 128 * T_;

    // staging assignments (512 threads)
    const int k0r0 = tid >> 5,         k0c0 = tid & 31;
    const int k0r1 = (tid + 512) >> 5, k0c1 = (tid + 512) & 31;
    const int v0d0 = tid >> 2,         v0c0 = tid & 3;
    const int v0d1 = (tid + 512) >> 2, v0c1 = (tid + 512) & 3;
    const int k1r = tid >> 4, k1c = tid & 15;
    const int v1d = tid >> 2, v1c = tid & 3;

    const int nkt = 2 * qt + 2;
    const int qw = qt * 64 + w4 * 16;

    bf16x8 qf[8];
    if (cfg == 0) {
        const ushort* qb = qmix0 + (((size_t)b * 8 + kh) * T_ + qw + l16) * 256 + qtr * 8;
#pragma unroll
        for (int c = 0; c < 8; c++) qf[c] = *(const bf16x8*)(qb + c * 32);
    } else {
#pragma unroll
        for (int hI = 0; hI < 2; hI++) {
            const ushort* qb = qmix1 + (((size_t)b * 16 + 2 * kh + hI) * T_ + qw + l16) * 128 + qtr * 8;
#pragma unroll
            for (int c = 0; c < 4; c++) qf[hI * 4 + c] = *(const bf16x8*)(qb + c * 32);
        }
    }

    f32x4 acc[16];
    f32x4 accl[2] = {{0.f,0.f,0.f,0.f},{0.f,0.f,0.f,0.f}};
#pragma unroll
    for (int s = 0; s < 16; s++) acc[s] = (f32x4){0.f,0.f,0.f,0.f};

    const float scale2_0 = 0.0625f * 1.4426950408889634f;
    const float scale2_1 = 0.08838834764831845f * 1.4426950408889634f;

    uint4 k0a, k0b, v0a, v0b, k1a, v1a;
#define ISSUE(kt_) do {                                                              \
        k0a = *(const uint4*)(kg0 + (size_t)((kt_) * 32 + k0r0) * 256 + k0c0 * 8);   \
        k0b = *(const uint4*)(kg0 + (size_t)((kt_) * 32 + k0r1) * 256 + k0c1 * 8);   \
        v0a = *(const uint4*)(vg0 + (size_t)v0d0 * T_ + (kt_) * 32 + v0c0 * 8);      \
        v0b = *(const uint4*)(vg0 + (size_t)v0d1 * T_ + (kt_) * 32 + v0c1 * 8);      \
        k1a = *(const uint4*)(kg1 + (size_t)((kt_) * 32 + k1r) * 128 + k1c * 8);     \
        v1a = *(const uint4*)(vg1 + (size_t)v1d * T_ + (kt_) * 32 + v1c * 8);        \
    } while (0)
#define WRITE(base_) do {                                                            \
        *(uint4*)&lds[(base_) + KS0 + k0r0 * 256 + ((k0c0 ^ (k0r0 & 7)) * 8)] = k0a; \
        *(uint4*)&lds[(base_) + KS0 + k0r1 * 256 + ((k0c1 ^ (k0r1 & 7)) * 8)] = k0b; \
        *(uint4*)&lds[(base_) + VT0 + v0d0 * 32 + ((v0c0 ^ (v0d0 & 3)) * 8)] = v0a;  \
        *(uint4*)&lds[(base_) + VT0 + v0d1 * 32 + ((v0c1 ^ (v0d1 & 3)) * 8)] = v0b;  \
        *(uint4*)&lds[(base_) + KS1 + k1r * 128 + ((k1c ^ (k1r & 7)) * 8)] = k1a;    \
        *(uint4*)&lds[(base_) + VT1 + v1d * 32 + ((v1c ^ (v1d & 3)) * 8)] = v1a;     \
    } while (0)

    // prologue: stage tile 0 into buf0
    ISSUE(0);
    WRITE(0);
    asm volatile("s_waitcnt lgkmcnt(0)" ::: "memory");
    asm volatile("s_barrier" ::: "memory");

    for (int j = 0; j < nkt; j++) {
        const int lbase = (j & 1) * BSZ;
        const bool more = (j + 1 < nkt);
        if (more) ISSUE(j + 1);           // loads fly during compute

        const int kt32 = j * 32;
        if (kt32 <= qw + 15) {
            if (cfg == 0) {
                attn_inst<8, 16, 256, 1>(qf, acc, accl, lds, lbase + KS0, lbase + VT0,
                                         scale2_0, qw, kt32, qtr, l16);
            } else {
                attn_inst<4, 8, 128, 2>(qf, acc, accl, lds, lbase + KS1, lbase + VT1,
                                        scale2_1, qw, kt32, qtr, l16);
            }
        }
        if (more) {
            WRITE((~j & 1) * BSZ);        // stage tile j+1 into the other buffer
            asm volatile("s_waitcnt lgkmcnt(0)" ::: "memory");
        }
        asm volatile("s_barrier" ::: "memory");   // single barrier per iteration
    }
#undef ISSUE
#undef WRITE

    if (cfg == 0) {
        float linv[4];
#pragma unroll
        for (int rr = 0; rr < 4; rr++) linv[rr] = 1.f / accl[0][rr];
        float* ob = out + ((size_t)b * T_ + qw) * MAXH + kh * 256;
#pragma unroll
        for (int s = 0; s < 16; s++)
#pragma unroll
            for (int rr = 0; rr < 4; rr++)
                ob[(size_t)(qtr * 4 + rr) * MAXH + s * 16 + l16] = acc[s][rr] * linv[rr];
    }
    __syncthreads();   // full sync incl. vmcnt drain: cfg0 stores visible
    if (cfg == 1) {
        float linva[4], linvb[4];
#pragma unroll
        for (int rr = 0; rr < 4; rr++) { linva[rr] = 1.f / accl[0][rr]; linvb[rr] = 1.f / accl[1][rr]; }
        float* ob = out + ((size_t)b * T_ + qw) * MAXH + kh * 256;
#pragma unroll
        for (int s = 0; s < 8; s++)
#pragma unroll
            for (int rr = 0; rr < 4; rr++)
                ob[(size_t)(qtr * 4 + rr) * MAXH + s * 16 + l16] += acc[s][rr] * linva[rr];
#pragma unroll
        for (int s = 0; s < 8; s++)
#pragma unroll
            for (int rr = 0; rr < 4; rr++)
                ob[(size_t)(qtr * 4 + rr) * MAXH + 128 + s * 16 + l16] += acc[8 + s][rr] * linvb[rr];
    }
}

extern "C" void kernel_launch(void* const* d_in, const int* in_sizes, int n_in,
                              void* d_out, int out_size, void* d_ws, size_t ws_size,
                              hipStream_t stream) {
    const float* q_m = (const float*)d_in[0];
    const float* k_m = (const float*)d_in[1];
    const float* v_m = (const float*)d_in[2];
    const float* wts = (const float*)d_in[3];
    // d_in[4] attention_mask == causal tril (applied analytically)
    // d_in[5] position_ids == arange(T) (pos == t)
    float* out = (float*)d_out;
    ushort* ws = (ushort*)d_ws;

    ushort* qmix0 = ws;                 // (4,8,1024,256)   8M
    ushort* kmix0 = ws + 8388608u;      // (4,8,1024,256)   8M
    ushort* vt0   = ws + 16777216u;     // (4,8,256,1024)   8M (transposed)
    ushort* qmix1 = ws + 25165824u;     // (4,16,1024,128)  8M
    ushort* kmix1 = ws + 33554432u;     // (4,8,1024,128)   4M
    ushort* vt1   = ws + 37748736u;     // (4,8,128,1024)   4M (transposed)

    // weights l: 0:(h8,e1024) 1:(h8,e2048) 2:(h16,e1024) 3:(h16,e2048)
    mix_all<<<dim3(20480), dim3(256), 0, stream>>>(q_m, k_m, v_m, wts,
                                                   qmix0, kmix0, vt0, qmix1, kmix1, vt1);
    attn_fused<<<dim3(512), dim3(512), 0, stream>>>(qmix0, kmix0, vt0, qmix1, kmix1, vt1, out);
}